// Round 4
// baseline (326.683 us; speedup 1.0000x reference)
//
#include <hip/hip_runtime.h>
#include <hip/hip_bf16.h>
#include <math.h>

// Problem constants (fixed by reference)
#define NN 100000   // nodes
#define FF 128      // features
#define DD 16       // degree
#define KK 8        // hashers
#define HH 256      // hash dim
#define OO 256      // out dim
#define KH 2048     // K*H
#define TASKS 6250  // 100000 / 16 rows per task (exact)
#define BPAD 280    // LDS B row stride in shorts: 560 B = 35x16 (aligned), 140 dw % 32 = 12 -> 2-way banks (free)

// out[n,o] = ELU( sum_f nm[n,f]*An[f,o] + sum_f x[n,f]*As[f,o] + bias[o] )
// An = R_flat @ Wn^T, As = R_flat @ Ws^T  (256x256 collapsed weight, bf16)
// Fused kernel: B in LDS once per block; waves pull 16-row tasks from atomic queue,
// gather-mean neighbors directly into MFMA A-frag layout, 128 MFMAs, bias+ELU store.
// R4: counter zeroed in k_comb (in-dispatch store), NOT via hipMemsetAsync — a captured
// 4-B memset node was the prime suspect for calls-2+ skipping leading tasks (absmax 67).

using frag_t  = __attribute__((ext_vector_type(8))) short;   // 8 bf16 = 4 VGPR (MFMA A/B frag)
using f32x4   = __attribute__((ext_vector_type(4))) float;   // MFMA C/D frag
using ushort8 = __attribute__((ext_vector_type(8))) unsigned short;

static __device__ __forceinline__ float u2f(unsigned int u) {
    union { unsigned int i; float f; } v; v.i = u; return v.f;
}
static __device__ __forceinline__ unsigned short f2bf(float f) {
    union { float f; unsigned int i; } v; v.f = f;
    unsigned int x = v.i;
    x += 0x7fffu + ((x >> 16) & 1u);   // round-to-nearest-even
    return (unsigned short)(x >> 16);
}

// ---------------- Kernel 1: cast x (fp32) -> xb (bf16), 8 elem/thread ----------------
__global__ __launch_bounds__(256) void k_cast(const float* __restrict__ x,
                                              unsigned short* __restrict__ xb) {
    int t = blockIdx.x * 256 + threadIdx.x;      // 1.6M threads, 8 floats each
    const float4* xv = (const float4*)x;
    float4 a = xv[2 * t], b = xv[2 * t + 1];
    ushort8 o;
    o[0] = f2bf(a.x); o[1] = f2bf(a.y); o[2] = f2bf(a.z); o[3] = f2bf(a.w);
    o[4] = f2bf(b.x); o[5] = f2bf(b.y); o[6] = f2bf(b.z); o[7] = f2bf(b.w);
    *(ushort8*)(xb + (size_t)t * 8) = o;
}

// ------- Kernel 2: weight precompute, fp32 tiled GEMM, K-split into 8 partials -------
__global__ __launch_bounds__(256) void k_wgemm(const float* __restrict__ R,
                                               const float* __restrict__ Ws,
                                               const float* __restrict__ Wn,
                                               float* __restrict__ P) {
    __shared__ float a_s[16][68];
    __shared__ float w_s[16][68];
    int bx = blockIdx.x, by = blockIdx.y, bz = blockIdx.z;
    const float* W = (bx < 2) ? Wn : Ws;          // f2 0..127 -> Wn (neigh), else Ws (self)
    int fbase = (bx & 1) * 64;
    int t = threadIdx.x;
    int tx = t & 15, ty = t >> 4;
    int lf = t >> 2;              // 0..63: ff (R row) / oo (W row)
    int j4 = (t & 3) * 4;         // 0,4,8,12
    float acc[4][4] = {};
    const float* Rb = R + (size_t)bz * (FF * HH) + (size_t)(fbase + lf) * HH;
    const float* Wb = W + (size_t)(by * 64 + lf) * KH + (size_t)bz * 256;
    for (int ks = 0; ks < 16; ++ks) {
        float4 av = *(const float4*)(Rb + ks * 16 + j4);
        float4 wv = *(const float4*)(Wb + ks * 16 + j4);
        __syncthreads();
        a_s[j4 + 0][lf] = av.x; a_s[j4 + 1][lf] = av.y;
        a_s[j4 + 2][lf] = av.z; a_s[j4 + 3][lf] = av.w;
        w_s[j4 + 0][lf] = wv.x; w_s[j4 + 1][lf] = wv.y;
        w_s[j4 + 2][lf] = wv.z; w_s[j4 + 3][lf] = wv.w;
        __syncthreads();
#pragma unroll
        for (int jj = 0; jj < 16; ++jj) {
            float ar[4], wr[4];
#pragma unroll
            for (int i = 0; i < 4; ++i) ar[i] = a_s[jj][ty * 4 + i];
#pragma unroll
            for (int j = 0; j < 4; ++j) wr[j] = w_s[jj][tx * 4 + j];
#pragma unroll
            for (int i = 0; i < 4; ++i)
#pragma unroll
                for (int j = 0; j < 4; ++j) acc[i][j] += ar[i] * wr[j];
        }
    }
    float* Pb = P + (size_t)bz * 65536 + (size_t)(bx * 64) * 256 + by * 64;
#pragma unroll
    for (int i = 0; i < 4; ++i) {
        float4 v = make_float4(acc[i][0], acc[i][1], acc[i][2], acc[i][3]);
        *(float4*)(Pb + (size_t)(ty * 4 + i) * 256 + tx * 4) = v;
    }
}

// ---- Kernel 3: combine 8 partials, transpose to Bbf[o][f2] (bf16); zero task counter ----
__global__ __launch_bounds__(256) void k_comb(const float* __restrict__ P,
                                              unsigned short* __restrict__ Bbf,
                                              unsigned int* __restrict__ counter) {
    __shared__ float tsh[64][65];
    int bf = blockIdx.x, bo = blockIdx.y;    // 4x4 tiles of 64
    int t = threadIdx.x;
    if (bf == 0 && bo == 0 && t == 0) *counter = 0u;   // stream-ordered init for k_fused
    for (int e = t; e < 4096; e += 256) {
        int r = e >> 6, c = e & 63;
        float s = 0.f;
#pragma unroll
        for (int z = 0; z < 8; ++z)
            s += P[(size_t)z * 65536 + (size_t)(bf * 64 + r) * 256 + bo * 64 + c];
        tsh[r][c] = s;
    }
    __syncthreads();
    for (int e = t; e < 4096; e += 256) {
        int r = e >> 6, c = e & 63;
        Bbf[(size_t)(bo * 64 + r) * 256 + bf * 64 + c] = f2bf(tsh[c][r]);
    }
}

// ---------------- Kernel 4: fused gather-mean + MFMA GEMM + bias + ELU ----------------
// Block: 512 thr (8 waves), grid 256, 1 block/CU (LDS 144 KB). Barrier-free main loop.
// Wave task = 16 output rows. A-frag built in-register: lane(l15,quad) holds
// A[m0+l15][k = f*32 + quad*8 .. +7]; k 0..127 = neigh mean (fp32 acc -> bf16),
// k 128..255 = self feats. B[n][k] LDS-resident. C/D: col=l15, row=quad*4+reg.
__global__ __launch_bounds__(512, 1) void k_fused(const unsigned short* __restrict__ xb,
                                                  const int* __restrict__ nbr,
                                                  const unsigned short* __restrict__ Bbf,
                                                  const float* __restrict__ bias,
                                                  float* __restrict__ C,
                                                  unsigned int* __restrict__ counter) {
    extern __shared__ unsigned short Bls[];                    // [256][BPAD] shorts, then bias fp32[256]
    float* bias_ls = (float*)(Bls + 256 * BPAD);
    int t = threadIdx.x;
    // stage B: 256 rows x 32 chunks of 8 shorts = 8192 chunks, 16/thread
#pragma unroll
    for (int i = 0; i < 16; ++i) {
        int id = t + i * 512;
        int row = id >> 5, cc = id & 31;
        *(ushort8*)(Bls + row * BPAD + cc * 8) = *(const ushort8*)(Bbf + row * 256 + cc * 8);
    }
    if (t < 256) bias_ls[t] = bias[t];
    __syncthreads();

    int lane = t & 63;
    int l15 = lane & 15, quad = lane >> 4;

    for (;;) {
        unsigned int task;
        if (lane == 0) task = atomicAdd(counter, 1u);
        task = __builtin_amdgcn_readfirstlane(task);
        if (task >= TASKS) break;
        int m0 = (int)task * 16;
        int row = m0 + l15;

        // neighbor indices for this lane's row (redundant across quads; L2-cached)
        const int4* nb = (const int4*)(nbr + (size_t)row * 16);
        int4 i0 = nb[0], i1 = nb[1], i2 = nb[2], i3 = nb[3];
        int idxv[16] = { i0.x, i0.y, i0.z, i0.w, i1.x, i1.y, i1.z, i1.w,
                         i2.x, i2.y, i2.z, i2.w, i3.x, i3.y, i3.z, i3.w };

        f32x4 acc[16] = {};

        // ---- neigh half: k-frags f=0..3 (k = f*32 + quad*8) ----
#pragma unroll
        for (int f = 0; f < 4; ++f) {
            float s[8] = {0.f, 0.f, 0.f, 0.f, 0.f, 0.f, 0.f, 0.f};
            const unsigned short* base = xb + quad * 8 + f * 32;
#pragma unroll
            for (int d = 0; d < 16; ++d) {
                uint4 w = *(const uint4*)(base + (size_t)idxv[d] * 128);
                s[0] += u2f(w.x << 16);  s[1] += u2f(w.x & 0xffff0000u);
                s[2] += u2f(w.y << 16);  s[3] += u2f(w.y & 0xffff0000u);
                s[4] += u2f(w.z << 16);  s[5] += u2f(w.z & 0xffff0000u);
                s[6] += u2f(w.w << 16);  s[7] += u2f(w.w & 0xffff0000u);
            }
            frag_t af;
#pragma unroll
            for (int j = 0; j < 8; ++j) af[j] = (short)f2bf(s[j] * 0.0625f);
#pragma unroll
            for (int j = 0; j < 16; ++j) {
                frag_t bfr = *(const frag_t*)(Bls + (j * 16 + l15) * BPAD + f * 32 + quad * 8);
                acc[j] = __builtin_amdgcn_mfma_f32_16x16x32_bf16(af, bfr, acc[j], 0, 0, 0);
            }
        }
        // ---- self half: k-frags f=4..7 (k = f*32 + quad*8 -> xb col (f-4)*32 + quad*8) ----
#pragma unroll
        for (int f = 4; f < 8; ++f) {
            frag_t af = *(const frag_t*)(xb + (size_t)row * 128 + (f - 4) * 32 + quad * 8);
#pragma unroll
            for (int j = 0; j < 16; ++j) {
                frag_t bfr = *(const frag_t*)(Bls + (j * 16 + l15) * BPAD + f * 32 + quad * 8);
                acc[j] = __builtin_amdgcn_mfma_f32_16x16x32_bf16(af, bfr, acc[j], 0, 0, 0);
            }
        }
        // ---- epilogue: bias + ELU, fp32 store ----
        int r0 = m0 + quad * 4;
#pragma unroll
        for (int j = 0; j < 16; ++j) {
            int col = j * 16 + l15;
            float bv = bias_ls[col];
#pragma unroll
            for (int r = 0; r < 4; ++r) {
                float v = acc[j][r] + bv;
                C[(size_t)(r0 + r) * 256 + col] = (v > 0.f) ? v : expm1f(v);
            }
        }
    }
}

// ---------------------------------- launcher ----------------------------------
extern "C" void kernel_launch(void* const* d_in, const int* in_sizes, int n_in,
                              void* d_out, int out_size, void* d_ws, size_t ws_size,
                              hipStream_t stream) {
    const float* x    = (const float*)d_in[0];
    const int*   nbr  = (const int*)d_in[1];
    const float* R    = (const float*)d_in[2];
    const float* Ws   = (const float*)d_in[3];
    const float* Wn   = (const float*)d_in[4];
    const float* bias = (const float*)d_in[5];
    float* out = (float*)d_out;

    // workspace layout (16B-aligned): xb 25.6MB | P 2MB | Bbf 128KB | counter 4B
    char* ws = (char*)d_ws;
    unsigned short* xb  = (unsigned short*)(ws);
    float*          P   = (float*)(ws + 25600000);
    unsigned short* Bbf = (unsigned short*)(ws + 25600000 + 2097152);
    unsigned int*   cnt = (unsigned int*)(ws + 25600000 + 2097152 + 131072);

    const int lds_bytes = 256 * BPAD * 2 + 256 * 4;   // 143360 + 1024 = 144384 B
    hipFuncSetAttribute((const void*)k_fused,
                        hipFuncAttributeMaxDynamicSharedMemorySize, lds_bytes);

    hipLaunchKernelGGL(k_cast,  dim3(6250),    dim3(256), 0, stream, x, xb);
    hipLaunchKernelGGL(k_wgemm, dim3(4, 4, 8), dim3(256), 0, stream, R, Ws, Wn, P);
    hipLaunchKernelGGL(k_comb,  dim3(4, 4),    dim3(256), 0, stream, P, Bbf, cnt);
    hipLaunchKernelGGL(k_fused, dim3(256), dim3(512), lds_bytes, stream,
                       xb, nbr, Bbf, bias, out, cnt);
}